// Round 6
// baseline (698.624 us; speedup 1.0000x reference)
//
#include <hip/hip_runtime.h>
#include <cstdint>
#include <cstddef>

#define NFEAT 128
#define NPROTO 50
#define NCLS 10

typedef __attribute__((ext_vector_type(8))) short short8;    // 8 x bf16
typedef __attribute__((ext_vector_type(4))) float floatx4;

// ---------------- CSR build ----------------

__global__ __launch_bounds__(256) void count_kernel(const int* __restrict__ dst,
                                                    int* __restrict__ cnt, int E) {
  int e = blockIdx.x * 256 + threadIdx.x;
  if (e < E) atomicAdd(&cnt[dst[e]], 1);
}

__global__ __launch_bounds__(1024) void scan_kernel(const int* __restrict__ cnt,
                                                    int* __restrict__ row_ptr, int Nn) {
  __shared__ int sums[1024];
  int t = threadIdx.x;
  int CH = (Nn + 1023) >> 10;
  int lo = t * CH, hi = min(lo + CH, Nn);
  int s = 0;
  for (int i = lo; i < hi; ++i) s += cnt[i];
  sums[t] = s;
  __syncthreads();
  for (int off = 1; off < 1024; off <<= 1) {
    int v = sums[t];
    int add = (t >= off) ? sums[t - off] : 0;
    __syncthreads();
    sums[t] = v + add;
    __syncthreads();
  }
  int run = (t == 0) ? 0 : sums[t - 1];
  for (int i = lo; i < hi; ++i) { row_ptr[i] = run; run += cnt[i]; }
  if (t == 1023) row_ptr[Nn] = sums[1023];
}

__global__ __launch_bounds__(256) void dis_kernel(const int* __restrict__ cnt,
                                                  float* __restrict__ dis, int Nn) {
  int i = blockIdx.x * 256 + threadIdx.x;
  if (i < Nn) dis[i] = 1.0f / sqrtf((float)(cnt[i] + 1));  // +1: self-loop
}

__global__ __launch_bounds__(256) void fill_kernel(const int* __restrict__ src,
                                                   const int* __restrict__ dst,
                                                   const int* __restrict__ row_ptr,
                                                   int* __restrict__ cursor,
                                                   int* __restrict__ csr_src, int E) {
  int e = blockIdx.x * 256 + threadIdx.x;
  if (e < E) {
    int d = dst[e];
    int pos = atomicAdd(&cursor[d], 1);
    csr_src[row_ptr[d] + pos] = src[e];
  }
}

// ---------------- fp32 -> bf16 hi/lo split ----------------

__device__ __forceinline__ void split1(float v, unsigned short& h, unsigned short& l) {
  unsigned int b = __float_as_uint(v);
  h = (unsigned short)(b >> 16);
  float r = v - __uint_as_float(b & 0xFFFF0000u);
  l = (unsigned short)(__float_as_uint(r) >> 16);
}

__global__ __launch_bounds__(256) void wconv_kernel(const float* __restrict__ W,
                                                    unsigned short* __restrict__ Wh,
                                                    unsigned short* __restrict__ Wl, int n) {
  int i = blockIdx.x * 256 + threadIdx.x;
  if (i < n) {
    unsigned short h, l;
    split1(W[i], h, l);
    Wh[i] = h; Wl[i] = l;
  }
}

// protos: split to bf16 hi/lo padded to 64 rows, plus squared norms
__global__ __launch_bounds__(128)
void psplit_kernel(const float* __restrict__ proto, unsigned short* __restrict__ Ph,
                   unsigned short* __restrict__ Pl, float* __restrict__ pn) {
  int t = threadIdx.x;
  for (int idx = t; idx < 64 * 128; idx += 128) {
    int p = idx >> 7;
    float v = (p < NPROTO) ? proto[p * 128 + (idx & 127)] : 0.f;
    unsigned short h, l;
    split1(v, h, l);
    Ph[idx] = h; Pl[idx] = l;
  }
  if (t < 64) {
    float s = 0.f;
    if (t < NPROTO)
      for (int f = 0; f < 128; ++f) { float v = proto[t * 128 + f]; s += v * v; }
    pn[t] = s;
  }
}

// ---------------- MFMA GEMM v4: C[M,128] = A[M,K] @ W[128,K]^T ----------------
// Parallelism-first: wave = 16 rows x 64 cols (4 n-tiles), block = 4 waves =
// 32 rows x 128 cols. Grid = M/32 blocks -> ~6256 waves = 24/CU (6/SIMD),
// 4x round-5. No LDS, no barriers; W (<=512 KB) served by L1/L2 across waves.
// K is a template constant so the K-loop fully unrolls and loads pipeline.
// MODE 0: A fp32, rows scaled by dis[], split to bf16 hi/lo in-register.
// MODE 1: A pre-split bf16 hi/lo.

template<int MODE, int K>
__global__ __launch_bounds__(256, 4)
void gemm_v4(const float* __restrict__ Af32,
             const unsigned short* __restrict__ Ah, const unsigned short* __restrict__ Al,
             const float* __restrict__ dis,
             const unsigned short* __restrict__ Wh, const unsigned short* __restrict__ Wl,
             float* __restrict__ C, int M) {
  int t = threadIdx.x;
  int w = t >> 6, lane = t & 63;
  int col = lane & 15, quad = lane >> 4;
  int wr = w >> 1, wc = w & 1;
  int m0 = blockIdx.x * 32 + wr * 16;

  floatx4 acc[4];
#pragma unroll
  for (int b = 0; b < 4; ++b) acc[b] = floatx4{0.f, 0.f, 0.f, 0.f};

  int r = m0 + col;
  int row0 = r < M ? r : M - 1;
  float d0 = (MODE == 0) ? dis[row0] : 0.f;

  const size_t abase = (size_t)row0 * K + quad * 8;
  const size_t bbase = (size_t)(wc * 64 + col) * K + quad * 8;

#pragma unroll
  for (int kc = 0; kc < K; kc += 32) {
    short8 ah, al;
    if (MODE == 0) {
      const float* p = Af32 + abase + kc;
      float4 va = *(const float4*)p;
      float4 vb = *(const float4*)(p + 4);
      float f[8] = {va.x, va.y, va.z, va.w, vb.x, vb.y, vb.z, vb.w};
#pragma unroll
      for (int j = 0; j < 8; ++j) {
        unsigned short h, l;
        split1(f[j] * d0, h, l);
        ah[j] = (short)h; al[j] = (short)l;
      }
    } else {
      ah = *(const short8*)(Ah + abase + kc);
      al = *(const short8*)(Al + abase + kc);
    }
#pragma unroll
    for (int nt = 0; nt < 4; ++nt) {
      size_t wo = bbase + (size_t)nt * 16 * K + kc;
      short8 bh = *(const short8*)(Wh + wo);
      short8 bl = *(const short8*)(Wl + wo);
      acc[nt] = __builtin_amdgcn_mfma_f32_16x16x32_bf16(ah, bh, acc[nt], 0, 0, 0);
      acc[nt] = __builtin_amdgcn_mfma_f32_16x16x32_bf16(al, bh, acc[nt], 0, 0, 0);
      acc[nt] = __builtin_amdgcn_mfma_f32_16x16x32_bf16(ah, bl, acc[nt], 0, 0, 0);
    }
  }

#pragma unroll
  for (int rr = 0; rr < 4; ++rr) {
    int m = m0 + quad * 4 + rr;
    if (m < M) {
#pragma unroll
      for (int nt = 0; nt < 4; ++nt)
        C[(size_t)m * NFEAT + wc * 64 + nt * 16 + col] = acc[nt][rr];
    }
  }
}

// ---------------- Aggregation ----------------
// m rows already carry dis[src]; out[i] = relu(dis[i]*(sum_{s->i} m[s] + m[i]) + b).
// Half-wave (32 lanes, float4) per node; 4-deep unroll -> 8 gathers in flight/wave.
// MODE 0: write next-layer input = dis[i]*out as bf16 hi/lo.  MODE 1: fp32 out.

template<int MODE>
__global__ __launch_bounds__(256)
void agg_kernel(const float* __restrict__ m, const int* __restrict__ row_ptr,
                const int* __restrict__ csr_src, const float* __restrict__ dis,
                const float* __restrict__ bias,
                unsigned int* __restrict__ out_h, unsigned int* __restrict__ out_l,
                float* __restrict__ out_f, int Nn) {
  int t = threadIdx.x;
  int w = t >> 6, lane = t & 63;
  int sub = lane >> 5, l = lane & 31;
  int i = blockIdx.x * 8 + w * 2 + sub;
  if (i >= Nn) return;
  const float4* m4 = (const float4*)m;
  float4 acc = m4[(size_t)i * 32 + l];             // self-loop term
  int e0 = row_ptr[i], e1 = row_ptr[i + 1];
  int e = e0;
  for (; e + 4 <= e1; e += 4) {
    int s0 = csr_src[e], s1 = csr_src[e + 1], s2 = csr_src[e + 2], s3 = csr_src[e + 3];
    float4 v0 = m4[(size_t)s0 * 32 + l];
    float4 v1 = m4[(size_t)s1 * 32 + l];
    float4 v2 = m4[(size_t)s2 * 32 + l];
    float4 v3 = m4[(size_t)s3 * 32 + l];
    acc.x += (v0.x + v1.x) + (v2.x + v3.x);
    acc.y += (v0.y + v1.y) + (v2.y + v3.y);
    acc.z += (v0.z + v1.z) + (v2.z + v3.z);
    acc.w += (v0.w + v1.w) + (v2.w + v3.w);
  }
  for (; e < e1; ++e) {
    int s = csr_src[e];
    float4 v = m4[(size_t)s * 32 + l];
    acc.x += v.x; acc.y += v.y; acc.z += v.z; acc.w += v.w;
  }
  float di = dis[i];
  float4 b = ((const float4*)bias)[l];
  float r0 = fmaxf(fmaf(di, acc.x, b.x), 0.f);
  float r1 = fmaxf(fmaf(di, acc.y, b.y), 0.f);
  float r2 = fmaxf(fmaf(di, acc.z, b.z), 0.f);
  float r3 = fmaxf(fmaf(di, acc.w, b.w), 0.f);
  if (MODE == 0) {
    unsigned short h0, l0, h1, l1, h2, l2, h3, l3;
    split1(di * r0, h0, l0);
    split1(di * r1, h1, l1);
    split1(di * r2, h2, l2);
    split1(di * r3, h3, l3);
    uint2 ph = make_uint2((unsigned int)h0 | ((unsigned int)h1 << 16),
                          (unsigned int)h2 | ((unsigned int)h3 << 16));
    uint2 pl = make_uint2((unsigned int)l0 | ((unsigned int)l1 << 16),
                          (unsigned int)l2 | ((unsigned int)l3 << 16));
    ((uint2*)out_h)[(size_t)i * 32 + l] = ph;
    ((uint2*)out_l)[(size_t)i * 32 + l] = pl;
  } else {
    ((float4*)out_f)[(size_t)i * 32 + l] = make_float4(r0, r1, r2, r3);
  }
}

// ---------------- Prototype head via MFMA ----------------

__global__ __launch_bounds__(256)
void proto_mfma(const float* __restrict__ emb,
                const unsigned short* __restrict__ Ph, const unsigned short* __restrict__ Pl,
                const float* __restrict__ pn, const float* __restrict__ lastw,
                float* __restrict__ out_logits, float* __restrict__ out_probs,
                float* __restrict__ out_dist, int Nn) {
  __shared__ float simS[64][65];
  int t = threadIdx.x;
  int w = t >> 6, lane = t & 63;
  int col = lane & 15, quad = lane >> 4;
  int m0 = blockIdx.x * 64 + w * 16;
  int row = m0 + col;
  int r0 = row < Nn ? row : Nn - 1;

  floatx4 acc[4];
#pragma unroll
  for (int nt = 0; nt < 4; ++nt) acc[nt] = floatx4{0.f, 0.f, 0.f, 0.f};

  float en = 0.f;
  const float* ap = emb + (size_t)r0 * 128 + quad * 8;
#pragma unroll
  for (int kc = 0; kc < 4; ++kc) {
    float4 va = *(const float4*)(ap + kc * 32);
    float4 vb = *(const float4*)(ap + kc * 32 + 4);
    float f[8] = {va.x, va.y, va.z, va.w, vb.x, vb.y, vb.z, vb.w};
    short8 ah, al;
#pragma unroll
    for (int j = 0; j < 8; ++j) {
      unsigned short h, l;
      split1(f[j], h, l);
      ah[j] = (short)h; al[j] = (short)l;
      en = fmaf(f[j], f[j], en);
    }
#pragma unroll
    for (int nt = 0; nt < 4; ++nt) {
      const unsigned short* bp = Ph + (size_t)(nt * 16 + col) * 128 + kc * 32 + quad * 8;
      const unsigned short* bq = Pl + (size_t)(nt * 16 + col) * 128 + kc * 32 + quad * 8;
      short8 bh = *(const short8*)bp;
      short8 bl = *(const short8*)bq;
      acc[nt] = __builtin_amdgcn_mfma_f32_16x16x32_bf16(ah, bh, acc[nt], 0, 0, 0);
      acc[nt] = __builtin_amdgcn_mfma_f32_16x16x32_bf16(al, bh, acc[nt], 0, 0, 0);
      acc[nt] = __builtin_amdgcn_mfma_f32_16x16x32_bf16(ah, bl, acc[nt], 0, 0, 0);
    }
  }
  en += __shfl_xor(en, 16);
  en += __shfl_xor(en, 32);

  float pnv[4];
#pragma unroll
  for (int nt = 0; nt < 4; ++nt) pnv[nt] = pn[nt * 16 + col];

#pragma unroll
  for (int r = 0; r < 4; ++r) {
    int node = m0 + quad * 4 + r;
    float enr = __shfl(en, quad * 4 + r);
    bool valid = node < Nn;
#pragma unroll
    for (int nt = 0; nt < 4; ++nt) {
      int p = nt * 16 + col;
      float d = enr - 2.f * acc[nt][r] + pnv[nt];
      float sim = (p < NPROTO) ? logf((d + 1.0f) / (d + 1e-4f)) : 0.f;
      simS[w * 16 + quad * 4 + r][p] = sim;
      if (valid && p < NPROTO) out_dist[(size_t)node * NPROTO + p] = d;
    }
  }
  __syncthreads();

  if (t < 64) {
    int node = blockIdx.x * 64 + t;
    if (node < Nn) {
      float sims[NPROTO];
#pragma unroll
      for (int p = 0; p < NPROTO; ++p) sims[p] = simS[t][p];
      float lg[NCLS];
      float mx = -1e30f;
#pragma unroll
      for (int c = 0; c < NCLS; ++c) {
        float s = 0.f;
#pragma unroll
        for (int p = 0; p < NPROTO; ++p) s = fmaf(sims[p], lastw[c * NPROTO + p], s);
        lg[c] = s;
        mx = fmaxf(mx, s);
      }
      float ss = 0.f;
#pragma unroll
      for (int c = 0; c < NCLS; ++c) ss += expf(lg[c] - mx);
      float inv = 1.f / ss;
#pragma unroll
      for (int c = 0; c < NCLS; ++c) {
        out_logits[(size_t)node * NCLS + c] = lg[c];
        out_probs[(size_t)node * NCLS + c] = expf(lg[c] - mx) * inv;
      }
    }
  }
}

// ---------------- launcher ----------------

extern "C" void kernel_launch(void* const* d_in, const int* in_sizes, int n_in,
                              void* d_out, int out_size, void* d_ws, size_t ws_size,
                              hipStream_t stream) {
  const float* x    = (const float*)d_in[0];
  const int*  eidx  = (const int*)d_in[1];
  const float* W1   = (const float*)d_in[2];
  const float* b1   = (const float*)d_in[3];
  const float* W2   = (const float*)d_in[4];
  const float* b2   = (const float*)d_in[5];
  const float* W3   = (const float*)d_in[6];
  const float* b3   = (const float*)d_in[7];
  const float* prot = (const float*)d_in[8];
  const float* lastw= (const float*)d_in[9];

  const int Nn = in_sizes[0] / 512;       // 50000
  const int E  = in_sizes[1] / 2;         // 640000
  const int* esrc = eidx;
  const int* edst = eidx + E;

  float* out        = (float*)d_out;
  float* out_logits = out;
  float* out_probs  = out + (size_t)Nn * NCLS;
  float* out_emb    = out + (size_t)Nn * 2 * NCLS;
  float* out_dist   = out_emb + (size_t)Nn * NFEAT;

  // workspace layout
  float* mbuf  = (float*)d_ws;                              // N*128 fp32
  unsigned int* hh = (unsigned int*)(mbuf + (size_t)Nn * NFEAT);
  unsigned int* hl = hh + (size_t)Nn * 64;
  unsigned short* W1h = (unsigned short*)(hl + (size_t)Nn * 64);   // 128*512
  unsigned short* W1l = W1h + 128 * 512;
  unsigned short* W2h = W1l + 128 * 512;                            // 128*128
  unsigned short* W2l = W2h + 128 * 128;
  unsigned short* W3h = W2l + 128 * 128;
  unsigned short* W3l = W3h + 128 * 128;
  unsigned short* Ph  = W3l + 128 * 128;                            // 64*128
  unsigned short* Pl  = Ph + 64 * 128;
  float* pn    = (float*)(Pl + 64 * 128);                   // 64
  int* cnt     = (int*)(pn + 64);                           // N
  float* dis   = (float*)(cnt + Nn);                        // N
  int* row_ptr = (int*)(dis + Nn);                          // N+1
  int* cursor  = row_ptr + Nn + 1;                          // N
  int* csr_src = cursor + Nn;                               // E

  hipMemsetAsync(cnt, 0, Nn * sizeof(int), stream);
  hipMemsetAsync(cursor, 0, Nn * sizeof(int), stream);
  count_kernel<<<(E + 255) / 256, 256, 0, stream>>>(edst, cnt, E);
  scan_kernel<<<1, 1024, 0, stream>>>(cnt, row_ptr, Nn);
  dis_kernel<<<(Nn + 255) / 256, 256, 0, stream>>>(cnt, dis, Nn);
  fill_kernel<<<(E + 255) / 256, 256, 0, stream>>>(esrc, edst, row_ptr, cursor, csr_src, E);

  wconv_kernel<<<(128 * 512 + 255) / 256, 256, 0, stream>>>(W1, W1h, W1l, 128 * 512);
  wconv_kernel<<<(128 * 128 + 255) / 256, 256, 0, stream>>>(W2, W2h, W2l, 128 * 128);
  wconv_kernel<<<(128 * 128 + 255) / 256, 256, 0, stream>>>(W3, W3h, W3l, 128 * 128);
  psplit_kernel<<<1, 128, 0, stream>>>(prot, Ph, Pl, pn);

  int gblocks = (Nn + 31) / 32;
  int ablocks = (Nn + 7) / 8;
  // layer 1: m = (dis . x) @ W1^T
  gemm_v4<0, 512><<<gblocks, 256, 0, stream>>>(x, nullptr, nullptr, dis, W1h, W1l, mbuf, Nn);
  agg_kernel<0><<<ablocks, 256, 0, stream>>>(mbuf, row_ptr, csr_src, dis, b1, hh, hl, nullptr, Nn);
  // layer 2
  gemm_v4<1, 128><<<gblocks, 256, 0, stream>>>(nullptr, (const unsigned short*)hh,
                                               (const unsigned short*)hl, dis, W2h, W2l, mbuf, Nn);
  agg_kernel<0><<<ablocks, 256, 0, stream>>>(mbuf, row_ptr, csr_src, dis, b2, hh, hl, nullptr, Nn);
  // layer 3 -> emb fp32 into d_out
  gemm_v4<1, 128><<<gblocks, 256, 0, stream>>>(nullptr, (const unsigned short*)hh,
                                               (const unsigned short*)hl, dis, W3h, W3l, mbuf, Nn);
  agg_kernel<1><<<ablocks, 256, 0, stream>>>(mbuf, row_ptr, csr_src, dis, b3, nullptr, nullptr, out_emb, Nn);

  proto_mfma<<<(Nn + 63) / 64, 256, 0, stream>>>(out_emb, Ph, Pl, pn, lastw,
                                                 out_logits, out_probs, out_dist, Nn);
}

// Round 7
// 598.624 us; speedup vs baseline: 1.1670x; 1.1670x over previous
//
#include <hip/hip_runtime.h>
#include <cstdint>
#include <cstddef>

#define NFEAT 128
#define NPROTO 50
#define NCLS 10

typedef __attribute__((ext_vector_type(8))) short short8;    // 8 x bf16
typedef __attribute__((ext_vector_type(4))) float floatx4;

// ---------------- CSR build ----------------

__global__ __launch_bounds__(256) void count_kernel(const int* __restrict__ dst,
                                                    int* __restrict__ cnt, int E) {
  int e = blockIdx.x * 256 + threadIdx.x;
  if (e < E) atomicAdd(&cnt[dst[e]], 1);
}

__global__ __launch_bounds__(1024) void scan_kernel(const int* __restrict__ cnt,
                                                    int* __restrict__ row_ptr, int Nn) {
  __shared__ int sums[1024];
  int t = threadIdx.x;
  int CH = (Nn + 1023) >> 10;
  int lo = t * CH, hi = min(lo + CH, Nn);
  int s = 0;
  for (int i = lo; i < hi; ++i) s += cnt[i];
  sums[t] = s;
  __syncthreads();
  for (int off = 1; off < 1024; off <<= 1) {
    int v = sums[t];
    int add = (t >= off) ? sums[t - off] : 0;
    __syncthreads();
    sums[t] = v + add;
    __syncthreads();
  }
  int run = (t == 0) ? 0 : sums[t - 1];
  for (int i = lo; i < hi; ++i) { row_ptr[i] = run; run += cnt[i]; }
  if (t == 1023) row_ptr[Nn] = sums[1023];
}

__global__ __launch_bounds__(256) void dis_kernel(const int* __restrict__ cnt,
                                                  float* __restrict__ dis, int Nn) {
  int i = blockIdx.x * 256 + threadIdx.x;
  if (i < Nn) dis[i] = 1.0f / sqrtf((float)(cnt[i] + 1));  // +1: self-loop
}

__global__ __launch_bounds__(256) void fill_kernel(const int* __restrict__ src,
                                                   const int* __restrict__ dst,
                                                   const int* __restrict__ row_ptr,
                                                   int* __restrict__ cursor,
                                                   int* __restrict__ csr_src, int E) {
  int e = blockIdx.x * 256 + threadIdx.x;
  if (e < E) {
    int d = dst[e];
    int pos = atomicAdd(&cursor[d], 1);
    csr_src[row_ptr[d] + pos] = src[e];
  }
}

// ---------------- fp32 -> bf16 hi/lo split ----------------

__device__ __forceinline__ void split1(float v, unsigned short& h, unsigned short& l) {
  unsigned int b = __float_as_uint(v);
  h = (unsigned short)(b >> 16);
  float r = v - __uint_as_float(b & 0xFFFF0000u);
  l = (unsigned short)(__float_as_uint(r) >> 16);
}

__global__ __launch_bounds__(256) void wconv_kernel(const float* __restrict__ W,
                                                    unsigned short* __restrict__ Wh,
                                                    unsigned short* __restrict__ Wl, int n) {
  int i = blockIdx.x * 256 + threadIdx.x;
  if (i < n) {
    unsigned short h, l;
    split1(W[i], h, l);
    Wh[i] = h; Wl[i] = l;
  }
}

// protos: split to bf16 hi/lo padded to 64 rows, plus squared norms
__global__ __launch_bounds__(128)
void psplit_kernel(const float* __restrict__ proto, unsigned short* __restrict__ Ph,
                   unsigned short* __restrict__ Pl, float* __restrict__ pn) {
  int t = threadIdx.x;
  for (int idx = t; idx < 64 * 128; idx += 128) {
    int p = idx >> 7;
    float v = (p < NPROTO) ? proto[p * 128 + (idx & 127)] : 0.f;
    unsigned short h, l;
    split1(v, h, l);
    Ph[idx] = h; Pl[idx] = l;
  }
  if (t < 64) {
    float s = 0.f;
    if (t < NPROTO)
      for (int f = 0; f < 128; ++f) { float v = proto[t * 128 + f]; s += v * v; }
    pn[t] = s;
  }
}

// ---------------- MFMA GEMM v5: C[M,128] = A[M,K] @ W[128,K]^T ----------------
// m97 blueprint: BOTH operands staged to LDS per BK=32 chunk through a
// register prefetch pipeline (8 independent coalesced loads/thread issued for
// chunk c+1 before computing chunk c). Fragments read from LDS with padded,
// 16B-aligned strides (<=2-way bank aliasing = free). Block 128x128, 4 waves
// 2x2 (wave 64x64 = 4mt x 4nt). 48 MFMA per wave-chunk.
// MODE 0: A fp32, scaled by dis[] at split time (layer 1, K=512).
// MODE 1: A pre-split bf16 hi/lo (layers 2/3, K=128).

template<int MODE, int K>
__global__ __launch_bounds__(256, 3)
void gemm_v5(const float* __restrict__ Af32,
             const unsigned short* __restrict__ Ah, const unsigned short* __restrict__ Al,
             const float* __restrict__ dis,
             const unsigned short* __restrict__ Wh, const unsigned short* __restrict__ Wl,
             float* __restrict__ C, int M) {
  constexpr int NCH = K / 32;
  constexpr int ASTR = 144;               // MODE0 A row stride (32 fp32 + pad), 16B-aligned
  constexpr int BSTR = 80;                // bf16 row stride (32 bf16 + pad), 16B-aligned
  __shared__ char lds[(MODE == 0) ? (128 * ASTR + 2 * 128 * BSTR)
                                  : (4 * 128 * BSTR)];
  char* ldsA  = lds;                                           // MODE0 fp32 / MODE1 Ah
  char* ldsA2 = lds + 128 * BSTR;                              // MODE1 Al
  char* ldsWh = (MODE == 0) ? (lds + 128 * ASTR) : (lds + 2 * 128 * BSTR);
  char* ldsWl = ldsWh + 128 * BSTR;

  int t = threadIdx.x;
  int w = t >> 6, lane = t & 63;
  int col = lane & 15, quad = lane >> 4;
  int wr = w >> 1, wc = w & 1;
  int m0 = blockIdx.x * 128;

  floatx4 acc[4][4];
#pragma unroll
  for (int a = 0; a < 4; ++a)
#pragma unroll
    for (int b = 0; b < 4; ++b) acc[a][b] = floatx4{0.f, 0.f, 0.f, 0.f};

  float dsc[4];
  if (MODE == 0) {
#pragma unroll
    for (int mt = 0; mt < 4; ++mt) {
      int r = m0 + wr * 64 + mt * 16 + col;
      dsc[mt] = dis[r < M ? r : M - 1];
    }
  }

  // ---- staging maps (kc-invariant parts) ----
  // MODE0 A: 4 units/thread, unit u = i*256+t: row=u>>3, c=u&7 (16B of fp32)
  // bf16 planes (W always; A in MODE1): 2 units/thread: row=u>>2, c=u&3 (16B)
  int arow[4], acol4[4];
  if (MODE == 0) {
#pragma unroll
    for (int i = 0; i < 4; ++i) {
      int u = i * 256 + t;
      int rw = u >> 3;
      arow[i] = (m0 + rw < M) ? (m0 + rw) : (M - 1);
      acol4[i] = u & 7;
    }
  }
  int a2row[2], a2col[2];
  if (MODE == 1) {
#pragma unroll
    for (int i = 0; i < 2; ++i) {
      int u = i * 256 + t;
      int rw = u >> 2;
      a2row[i] = (m0 + rw < M) ? (m0 + rw) : (M - 1);
      a2col[i] = u & 3;
    }
  }
  int wrow[2], wcol[2];
#pragma unroll
  for (int i = 0; i < 2; ++i) {
    int u = i * 256 + t;
    wrow[i] = u >> 2;
    wcol[i] = u & 3;
  }

  float4 pa[4];                 // MODE0 prefetch
  short8 paH[2], paL[2];        // MODE1 prefetch
  short8 pwH[2], pwL[2];

  auto load_chunk = [&](int kc) {
    if (MODE == 0) {
#pragma unroll
      for (int i = 0; i < 4; ++i)
        pa[i] = *(const float4*)(Af32 + (size_t)arow[i] * K + kc + acol4[i] * 4);
    } else {
#pragma unroll
      for (int i = 0; i < 2; ++i) {
        size_t off = (size_t)a2row[i] * K + kc + a2col[i] * 8;
        paH[i] = *(const short8*)(Ah + off);
        paL[i] = *(const short8*)(Al + off);
      }
    }
#pragma unroll
    for (int i = 0; i < 2; ++i) {
      size_t off = (size_t)wrow[i] * K + kc + wcol[i] * 8;
      pwH[i] = *(const short8*)(Wh + off);
      pwL[i] = *(const short8*)(Wl + off);
    }
  };

  auto write_chunk = [&]() {
    if (MODE == 0) {
#pragma unroll
      for (int i = 0; i < 4; ++i) {
        int u = i * 256 + t;
        *(float4*)(ldsA + (u >> 3) * ASTR + (u & 7) * 16) = pa[i];
      }
    } else {
#pragma unroll
      for (int i = 0; i < 2; ++i) {
        int u = i * 256 + t;
        int o = (u >> 2) * BSTR + (u & 3) * 16;
        *(short8*)(ldsA + o) = paH[i];
        *(short8*)(ldsA2 + o) = paL[i];
      }
    }
#pragma unroll
    for (int i = 0; i < 2; ++i) {
      int u = i * 256 + t;
      int o = (u >> 2) * BSTR + (u & 3) * 16;
      *(short8*)(ldsWh + o) = pwH[i];
      *(short8*)(ldsWl + o) = pwL[i];
    }
  };

  load_chunk(0);
  for (int c = 0; c < NCH; ++c) {
    if (c) __syncthreads();               // previous compute done; LDS reusable
    write_chunk();
    __syncthreads();                      // LDS valid
    if (c + 1 < NCH) load_chunk((c + 1) * 32);   // overlap with compute

    // A fragments for this wave's 4 m-tiles
    short8 ah[4], al[4];
#pragma unroll
    for (int mt = 0; mt < 4; ++mt) {
      int ra = wr * 64 + mt * 16 + col;
      if (MODE == 0) {
        float4 fa = *(const float4*)(ldsA + ra * ASTR + quad * 32);
        float4 fb = *(const float4*)(ldsA + ra * ASTR + quad * 32 + 16);
        float f[8] = {fa.x, fa.y, fa.z, fa.w, fb.x, fb.y, fb.z, fb.w};
#pragma unroll
        for (int j = 0; j < 8; ++j) {
          unsigned short h, l;
          split1(f[j] * dsc[mt], h, l);
          ah[mt][j] = (short)h; al[mt][j] = (short)l;
        }
      } else {
        int o = ra * BSTR + quad * 16;
        ah[mt] = *(const short8*)(ldsA + o);
        al[mt] = *(const short8*)(ldsA2 + o);
      }
    }
#pragma unroll
    for (int nt = 0; nt < 4; ++nt) {
      int rw = wc * 64 + nt * 16 + col;
      int o = rw * BSTR + quad * 16;
      short8 bh = *(const short8*)(ldsWh + o);
      short8 bl = *(const short8*)(ldsWl + o);
#pragma unroll
      for (int mt = 0; mt < 4; ++mt) {
        acc[mt][nt] = __builtin_amdgcn_mfma_f32_16x16x32_bf16(ah[mt], bh, acc[mt][nt], 0, 0, 0);
        acc[mt][nt] = __builtin_amdgcn_mfma_f32_16x16x32_bf16(al[mt], bh, acc[mt][nt], 0, 0, 0);
        acc[mt][nt] = __builtin_amdgcn_mfma_f32_16x16x32_bf16(ah[mt], bl, acc[mt][nt], 0, 0, 0);
      }
    }
  }

#pragma unroll
  for (int mt = 0; mt < 4; ++mt)
#pragma unroll
    for (int r = 0; r < 4; ++r) {
      int m = m0 + wr * 64 + mt * 16 + quad * 4 + r;
      if (m < M) {
#pragma unroll
        for (int nt = 0; nt < 4; ++nt)
          C[(size_t)m * NFEAT + wc * 64 + nt * 16 + col] = acc[mt][nt][r];
      }
    }
}

// ---------------- Aggregation ----------------
// m rows already carry dis[src]; out[i] = relu(dis[i]*(sum_{s->i} m[s] + m[i]) + b).
// Half-wave (32 lanes, float4) per node; 4-deep unroll -> 8 gathers in flight/wave.
// MODE 0: write next-layer input = dis[i]*out as bf16 hi/lo.  MODE 1: fp32 out.

template<int MODE>
__global__ __launch_bounds__(256)
void agg_kernel(const float* __restrict__ m, const int* __restrict__ row_ptr,
                const int* __restrict__ csr_src, const float* __restrict__ dis,
                const float* __restrict__ bias,
                unsigned int* __restrict__ out_h, unsigned int* __restrict__ out_l,
                float* __restrict__ out_f, int Nn) {
  int t = threadIdx.x;
  int w = t >> 6, lane = t & 63;
  int sub = lane >> 5, l = lane & 31;
  int i = blockIdx.x * 8 + w * 2 + sub;
  if (i >= Nn) return;
  const float4* m4 = (const float4*)m;
  float4 acc = m4[(size_t)i * 32 + l];             // self-loop term
  int e0 = row_ptr[i], e1 = row_ptr[i + 1];
  int e = e0;
  for (; e + 4 <= e1; e += 4) {
    int s0 = csr_src[e], s1 = csr_src[e + 1], s2 = csr_src[e + 2], s3 = csr_src[e + 3];
    float4 v0 = m4[(size_t)s0 * 32 + l];
    float4 v1 = m4[(size_t)s1 * 32 + l];
    float4 v2 = m4[(size_t)s2 * 32 + l];
    float4 v3 = m4[(size_t)s3 * 32 + l];
    acc.x += (v0.x + v1.x) + (v2.x + v3.x);
    acc.y += (v0.y + v1.y) + (v2.y + v3.y);
    acc.z += (v0.z + v1.z) + (v2.z + v3.z);
    acc.w += (v0.w + v1.w) + (v2.w + v3.w);
  }
  for (; e < e1; ++e) {
    int s = csr_src[e];
    float4 v = m4[(size_t)s * 32 + l];
    acc.x += v.x; acc.y += v.y; acc.z += v.z; acc.w += v.w;
  }
  float di = dis[i];
  float4 b = ((const float4*)bias)[l];
  float r0 = fmaxf(fmaf(di, acc.x, b.x), 0.f);
  float r1 = fmaxf(fmaf(di, acc.y, b.y), 0.f);
  float r2 = fmaxf(fmaf(di, acc.z, b.z), 0.f);
  float r3 = fmaxf(fmaf(di, acc.w, b.w), 0.f);
  if (MODE == 0) {
    unsigned short h0, l0, h1, l1, h2, l2, h3, l3;
    split1(di * r0, h0, l0);
    split1(di * r1, h1, l1);
    split1(di * r2, h2, l2);
    split1(di * r3, h3, l3);
    uint2 ph = make_uint2((unsigned int)h0 | ((unsigned int)h1 << 16),
                          (unsigned int)h2 | ((unsigned int)h3 << 16));
    uint2 pl = make_uint2((unsigned int)l0 | ((unsigned int)l1 << 16),
                          (unsigned int)l2 | ((unsigned int)l3 << 16));
    ((uint2*)out_h)[(size_t)i * 32 + l] = ph;
    ((uint2*)out_l)[(size_t)i * 32 + l] = pl;
  } else {
    ((float4*)out_f)[(size_t)i * 32 + l] = make_float4(r0, r1, r2, r3);
  }
}

// ---------------- Prototype head via MFMA ----------------

__global__ __launch_bounds__(256)
void proto_mfma(const float* __restrict__ emb,
                const unsigned short* __restrict__ Ph, const unsigned short* __restrict__ Pl,
                const float* __restrict__ pn, const float* __restrict__ lastw,
                float* __restrict__ out_logits, float* __restrict__ out_probs,
                float* __restrict__ out_dist, int Nn) {
  __shared__ float simS[64][65];
  int t = threadIdx.x;
  int w = t >> 6, lane = t & 63;
  int col = lane & 15, quad = lane >> 4;
  int m0 = blockIdx.x * 64 + w * 16;
  int row = m0 + col;
  int r0 = row < Nn ? row : Nn - 1;

  floatx4 acc[4];
#pragma unroll
  for (int nt = 0; nt < 4; ++nt) acc[nt] = floatx4{0.f, 0.f, 0.f, 0.f};

  float en = 0.f;
  const float* ap = emb + (size_t)r0 * 128 + quad * 8;
#pragma unroll
  for (int kc = 0; kc < 4; ++kc) {
    float4 va = *(const float4*)(ap + kc * 32);
    float4 vb = *(const float4*)(ap + kc * 32 + 4);
    float f[8] = {va.x, va.y, va.z, va.w, vb.x, vb.y, vb.z, vb.w};
    short8 ah, al;
#pragma unroll
    for (int j = 0; j < 8; ++j) {
      unsigned short h, l;
      split1(f[j], h, l);
      ah[j] = (short)h; al[j] = (short)l;
      en = fmaf(f[j], f[j], en);
    }
#pragma unroll
    for (int nt = 0; nt < 4; ++nt) {
      const unsigned short* bp = Ph + (size_t)(nt * 16 + col) * 128 + kc * 32 + quad * 8;
      const unsigned short* bq = Pl + (size_t)(nt * 16 + col) * 128 + kc * 32 + quad * 8;
      short8 bh = *(const short8*)bp;
      short8 bl = *(const short8*)bq;
      acc[nt] = __builtin_amdgcn_mfma_f32_16x16x32_bf16(ah, bh, acc[nt], 0, 0, 0);
      acc[nt] = __builtin_amdgcn_mfma_f32_16x16x32_bf16(al, bh, acc[nt], 0, 0, 0);
      acc[nt] = __builtin_amdgcn_mfma_f32_16x16x32_bf16(ah, bl, acc[nt], 0, 0, 0);
    }
  }
  en += __shfl_xor(en, 16);
  en += __shfl_xor(en, 32);

  float pnv[4];
#pragma unroll
  for (int nt = 0; nt < 4; ++nt) pnv[nt] = pn[nt * 16 + col];

#pragma unroll
  for (int r = 0; r < 4; ++r) {
    int node = m0 + quad * 4 + r;
    float enr = __shfl(en, quad * 4 + r);
    bool valid = node < Nn;
#pragma unroll
    for (int nt = 0; nt < 4; ++nt) {
      int p = nt * 16 + col;
      float d = enr - 2.f * acc[nt][r] + pnv[nt];
      float sim = (p < NPROTO) ? logf((d + 1.0f) / (d + 1e-4f)) : 0.f;
      simS[w * 16 + quad * 4 + r][p] = sim;
      if (valid && p < NPROTO) out_dist[(size_t)node * NPROTO + p] = d;
    }
  }
  __syncthreads();

  if (t < 64) {
    int node = blockIdx.x * 64 + t;
    if (node < Nn) {
      float sims[NPROTO];
#pragma unroll
      for (int p = 0; p < NPROTO; ++p) sims[p] = simS[t][p];
      float lg[NCLS];
      float mx = -1e30f;
#pragma unroll
      for (int c = 0; c < NCLS; ++c) {
        float s = 0.f;
#pragma unroll
        for (int p = 0; p < NPROTO; ++p) s = fmaf(sims[p], lastw[c * NPROTO + p], s);
        lg[c] = s;
        mx = fmaxf(mx, s);
      }
      float ss = 0.f;
#pragma unroll
      for (int c = 0; c < NCLS; ++c) ss += expf(lg[c] - mx);
      float inv = 1.f / ss;
#pragma unroll
      for (int c = 0; c < NCLS; ++c) {
        out_logits[(size_t)node * NCLS + c] = lg[c];
        out_probs[(size_t)node * NCLS + c] = expf(lg[c] - mx) * inv;
      }
    }
  }
}

// ---------------- launcher ----------------

extern "C" void kernel_launch(void* const* d_in, const int* in_sizes, int n_in,
                              void* d_out, int out_size, void* d_ws, size_t ws_size,
                              hipStream_t stream) {
  const float* x    = (const float*)d_in[0];
  const int*  eidx  = (const int*)d_in[1];
  const float* W1   = (const float*)d_in[2];
  const float* b1   = (const float*)d_in[3];
  const float* W2   = (const float*)d_in[4];
  const float* b2   = (const float*)d_in[5];
  const float* W3   = (const float*)d_in[6];
  const float* b3   = (const float*)d_in[7];
  const float* prot = (const float*)d_in[8];
  const float* lastw= (const float*)d_in[9];

  const int Nn = in_sizes[0] / 512;       // 50000
  const int E  = in_sizes[1] / 2;         // 640000
  const int* esrc = eidx;
  const int* edst = eidx + E;

  float* out        = (float*)d_out;
  float* out_logits = out;
  float* out_probs  = out + (size_t)Nn * NCLS;
  float* out_emb    = out + (size_t)Nn * 2 * NCLS;
  float* out_dist   = out_emb + (size_t)Nn * NFEAT;

  // workspace layout
  float* mbuf  = (float*)d_ws;                              // N*128 fp32
  unsigned int* hh = (unsigned int*)(mbuf + (size_t)Nn * NFEAT);
  unsigned int* hl = hh + (size_t)Nn * 64;
  unsigned short* W1h = (unsigned short*)(hl + (size_t)Nn * 64);   // 128*512
  unsigned short* W1l = W1h + 128 * 512;
  unsigned short* W2h = W1l + 128 * 512;                            // 128*128
  unsigned short* W2l = W2h + 128 * 128;
  unsigned short* W3h = W2l + 128 * 128;
  unsigned short* W3l = W3h + 128 * 128;
  unsigned short* Ph  = W3l + 128 * 128;                            // 64*128
  unsigned short* Pl  = Ph + 64 * 128;
  float* pn    = (float*)(Pl + 64 * 128);                   // 64
  int* cnt     = (int*)(pn + 64);                           // N
  float* dis   = (float*)(cnt + Nn);                        // N
  int* row_ptr = (int*)(dis + Nn);                          // N+1
  int* cursor  = row_ptr + Nn + 1;                          // N
  int* csr_src = cursor + Nn;                               // E

  hipMemsetAsync(cnt, 0, Nn * sizeof(int), stream);
  hipMemsetAsync(cursor, 0, Nn * sizeof(int), stream);
  count_kernel<<<(E + 255) / 256, 256, 0, stream>>>(edst, cnt, E);
  scan_kernel<<<1, 1024, 0, stream>>>(cnt, row_ptr, Nn);
  dis_kernel<<<(Nn + 255) / 256, 256, 0, stream>>>(cnt, dis, Nn);
  fill_kernel<<<(E + 255) / 256, 256, 0, stream>>>(esrc, edst, row_ptr, cursor, csr_src, E);

  wconv_kernel<<<(128 * 512 + 255) / 256, 256, 0, stream>>>(W1, W1h, W1l, 128 * 512);
  wconv_kernel<<<(128 * 128 + 255) / 256, 256, 0, stream>>>(W2, W2h, W2l, 128 * 128);
  wconv_kernel<<<(128 * 128 + 255) / 256, 256, 0, stream>>>(W3, W3h, W3l, 128 * 128);
  psplit_kernel<<<1, 128, 0, stream>>>(prot, Ph, Pl, pn);

  int gblocks = (Nn + 127) / 128;
  int ablocks = (Nn + 7) / 8;
  // layer 1: m = (dis . x) @ W1^T
  gemm_v5<0, 512><<<gblocks, 256, 0, stream>>>(x, nullptr, nullptr, dis, W1h, W1l, mbuf, Nn);
  agg_kernel<0><<<ablocks, 256, 0, stream>>>(mbuf, row_ptr, csr_src, dis, b1, hh, hl, nullptr, Nn);
  // layer 2
  gemm_v5<1, 128><<<gblocks, 256, 0, stream>>>(nullptr, (const unsigned short*)hh,
                                               (const unsigned short*)hl, dis, W2h, W2l, mbuf, Nn);
  agg_kernel<0><<<ablocks, 256, 0, stream>>>(mbuf, row_ptr, csr_src, dis, b2, hh, hl, nullptr, Nn);
  // layer 3 -> emb fp32 into d_out
  gemm_v5<1, 128><<<gblocks, 256, 0, stream>>>(nullptr, (const unsigned short*)hh,
                                               (const unsigned short*)hl, dis, W3h, W3l, mbuf, Nn);
  agg_kernel<1><<<ablocks, 256, 0, stream>>>(mbuf, row_ptr, csr_src, dis, b3, nullptr, nullptr, out_emb, Nn);

  proto_mfma<<<(Nn + 63) / 64, 256, 0, stream>>>(out_emb, Ph, Pl, pn, lastw,
                                                 out_logits, out_probs, out_dist, Nn);
}

// Round 8
// 563.757 us; speedup vs baseline: 1.2392x; 1.0618x over previous
//
#include <hip/hip_runtime.h>
#include <cstdint>
#include <cstddef>

#define NFEAT 128
#define NPROTO 50
#define NCLS 10

typedef __attribute__((ext_vector_type(8))) short short8;    // 8 x bf16
typedef __attribute__((ext_vector_type(4))) float floatx4;

// ---------------- CSR build ----------------

__global__ __launch_bounds__(256) void count_kernel(const int* __restrict__ dst,
                                                    int* __restrict__ cnt, int E) {
  int e = blockIdx.x * 256 + threadIdx.x;
  if (e < E) atomicAdd(&cnt[dst[e]], 1);
}

__global__ __launch_bounds__(1024) void scan_kernel(const int* __restrict__ cnt,
                                                    int* __restrict__ row_ptr, int Nn) {
  __shared__ int sums[1024];
  int t = threadIdx.x;
  int CH = (Nn + 1023) >> 10;
  int lo = t * CH, hi = min(lo + CH, Nn);
  int s = 0;
  for (int i = lo; i < hi; ++i) s += cnt[i];
  sums[t] = s;
  __syncthreads();
  for (int off = 1; off < 1024; off <<= 1) {
    int v = sums[t];
    int add = (t >= off) ? sums[t - off] : 0;
    __syncthreads();
    sums[t] = v + add;
    __syncthreads();
  }
  int run = (t == 0) ? 0 : sums[t - 1];
  for (int i = lo; i < hi; ++i) { row_ptr[i] = run; run += cnt[i]; }
  if (t == 1023) row_ptr[Nn] = sums[1023];
}

__global__ __launch_bounds__(256) void dis_kernel(const int* __restrict__ cnt,
                                                  float* __restrict__ dis, int Nn) {
  int i = blockIdx.x * 256 + threadIdx.x;
  if (i < Nn) dis[i] = 1.0f / sqrtf((float)(cnt[i] + 1));  // +1: self-loop
}

__global__ __launch_bounds__(256) void fill_kernel(const int* __restrict__ src,
                                                   const int* __restrict__ dst,
                                                   const int* __restrict__ row_ptr,
                                                   int* __restrict__ cursor,
                                                   int* __restrict__ csr_src, int E) {
  int e = blockIdx.x * 256 + threadIdx.x;
  if (e < E) {
    int d = dst[e];
    int pos = atomicAdd(&cursor[d], 1);
    csr_src[row_ptr[d] + pos] = src[e];
  }
}

// ---------------- fp32 -> bf16 hi/lo split ----------------

__device__ __forceinline__ void split1(float v, unsigned short& h, unsigned short& l) {
  unsigned int b = __float_as_uint(v);
  h = (unsigned short)(b >> 16);
  float r = v - __uint_as_float(b & 0xFFFF0000u);
  l = (unsigned short)(__float_as_uint(r) >> 16);
}

__global__ __launch_bounds__(256) void wconv_kernel(const float* __restrict__ W,
                                                    unsigned short* __restrict__ Wh,
                                                    unsigned short* __restrict__ Wl, int n) {
  int i = blockIdx.x * 256 + threadIdx.x;
  if (i < n) {
    unsigned short h, l;
    split1(W[i], h, l);
    Wh[i] = h; Wl[i] = l;
  }
}

// protos: split to bf16 hi/lo padded to 64 rows, plus squared norms
__global__ __launch_bounds__(128)
void psplit_kernel(const float* __restrict__ proto, unsigned short* __restrict__ Ph,
                   unsigned short* __restrict__ Pl, float* __restrict__ pn) {
  int t = threadIdx.x;
  for (int idx = t; idx < 64 * 128; idx += 128) {
    int p = idx >> 7;
    float v = (p < NPROTO) ? proto[p * 128 + (idx & 127)] : 0.f;
    unsigned short h, l;
    split1(v, h, l);
    Ph[idx] = h; Pl[idx] = l;
  }
  if (t < 64) {
    float s = 0.f;
    if (t < NPROTO)
      for (int f = 0; f < 128; ++f) { float v = proto[t * 128 + f]; s += v * v; }
    pn[t] = s;
  }
}

// ---------------- persistent-W streaming GEMM, layer 1 ----------------
// C[M,128] = (dis.*A[M,512]) @ W1[128,512]^T, W1 as bf16-hi only (2-product
// split on A keeps A at fp32 precision; W rounding ~2^-9 rel).
// Block = 512 thr = 8 waves; wave = one 32-row tile x 128 cols, fully
// independent K-loop: NO barriers inside (only 2, around the W-phase loads).
// W phase (256 k) lives in LDS fragment-linear (conflict-free b128 reads).
// A streams through a depth-4 rolling register prefetch (16 loads in flight).

__global__ __launch_bounds__(512, 2)
void gemm_p1(const float* __restrict__ A, const float* __restrict__ dis,
             const unsigned short* __restrict__ Wh,
             float* __restrict__ C, int M) {
  __shared__ short8 Wlds[4096];            // 64 KB: one 128x256 bf16 W phase
  int t = threadIdx.x;
  int w = t >> 6, lane = t & 63;
  int col = lane & 15, quad = lane >> 4;
  int ntiles = (M + 31) >> 5;
  int tile = blockIdx.x * 8 + w;
  if (tile >= ntiles) tile = ntiles - 1;   // dup of last tile: benign same-value stores
  int m0 = tile * 32;

  floatx4 acc[2][8];
#pragma unroll
  for (int a = 0; a < 2; ++a)
#pragma unroll
    for (int b = 0; b < 8; ++b) acc[a][b] = floatx4{0.f, 0.f, 0.f, 0.f};

  int row[2]; float dsc[2];
#pragma unroll
  for (int mt = 0; mt < 2; ++mt) {
    int r = m0 + mt * 16 + col;
    row[2 - 1 - (1 - mt)] = 0;             // no-op to keep layout simple
    row[mt] = r < M ? r : M - 1;
    dsc[mt] = dis[row[mt]];
  }

  for (int p = 0; p < 2; ++p) {
    const int kb = p * 256;
    // ---- stage W phase: 4096 units, fragment-linear (g,q,c) ----
    __syncthreads();                       // phase p-1 consumers done
#pragma unroll
    for (int i = 0; i < 8; ++i) {
      int u = i * 512 + t;
      int g = u >> 9, q = (u >> 4) & 31, c = u & 15;
      const unsigned short* src = Wh + (size_t)(g * 16 + c) * 512 + kb + q * 8;
      __builtin_amdgcn_global_load_lds(
          (const __attribute__((address_space(1))) void*)src,
          (__attribute__((address_space(3))) void*)((char*)Wlds + (size_t)(i * 512 + w * 64) * 16),
          16, 0, 0);
    }
    __syncthreads();                       // W phase valid

    // ---- stream 8 chunks of 32 k, depth-4 rolling prefetch ----
    float4 pf[4][2][2];                    // [slot][mt][half]
#pragma unroll
    for (int c0 = 0; c0 < 4; ++c0)
#pragma unroll
      for (int mt = 0; mt < 2; ++mt) {
        const float* pp = A + (size_t)row[mt] * 512 + kb + c0 * 32 + quad * 8;
        pf[c0][mt][0] = *(const float4*)pp;
        pf[c0][mt][1] = *(const float4*)(pp + 4);
      }
#pragma unroll
    for (int ck = 0; ck < 8; ++ck) {
      short8 ah[2], al[2];
#pragma unroll
      for (int mt = 0; mt < 2; ++mt) {
        float4 va = pf[ck & 3][mt][0];
        float4 vb = pf[ck & 3][mt][1];
        float f[8] = {va.x, va.y, va.z, va.w, vb.x, vb.y, vb.z, vb.w};
#pragma unroll
        for (int j = 0; j < 8; ++j) {
          unsigned short h, l;
          split1(f[j] * dsc[mt], h, l);
          ah[mt][j] = (short)h; al[mt][j] = (short)l;
        }
      }
      if (ck + 4 < 8) {
#pragma unroll
        for (int mt = 0; mt < 2; ++mt) {
          const float* pp = A + (size_t)row[mt] * 512 + kb + (ck + 4) * 32 + quad * 8;
          pf[ck & 3][mt][0] = *(const float4*)pp;
          pf[ck & 3][mt][1] = *(const float4*)(pp + 4);
        }
      }
#pragma unroll
      for (int nt = 0; nt < 8; ++nt) {
        int u = (nt * 32 + ck * 4 + quad) * 16 + col;
        short8 bh = Wlds[u];
#pragma unroll
        for (int mt = 0; mt < 2; ++mt) {
          acc[mt][nt] = __builtin_amdgcn_mfma_f32_16x16x32_bf16(ah[mt], bh, acc[mt][nt], 0, 0, 0);
          acc[mt][nt] = __builtin_amdgcn_mfma_f32_16x16x32_bf16(al[mt], bh, acc[mt][nt], 0, 0, 0);
        }
      }
    }
  }

#pragma unroll
  for (int mt = 0; mt < 2; ++mt)
#pragma unroll
    for (int r = 0; r < 4; ++r) {
      int m = m0 + mt * 16 + quad * 4 + r;
      if (m < M) {
#pragma unroll
        for (int nt = 0; nt < 8; ++nt)
          C[(size_t)m * NFEAT + nt * 16 + col] = acc[mt][nt][r];
      }
    }
}

// ---------------- persistent-W streaming GEMM, layers 2/3 ----------------
// C[M,128] = A@W^T, A pre-split bf16 hi/lo (pre-scaled), W hi+lo in LDS
// (64 KB, single load), 3-product split. One barrier pair total.

__global__ __launch_bounds__(512, 2)
void gemm_p2(const unsigned short* __restrict__ Ah, const unsigned short* __restrict__ Al,
             const unsigned short* __restrict__ Wh, const unsigned short* __restrict__ Wl,
             float* __restrict__ C, int M) {
  __shared__ short8 Wlds[4096];            // [plane 2][g 8][q 16][c 16]
  int t = threadIdx.x;
  int w = t >> 6, lane = t & 63;
  int col = lane & 15, quad = lane >> 4;
  int ntiles = (M + 31) >> 5;
  int tile = blockIdx.x * 8 + w;
  if (tile >= ntiles) tile = ntiles - 1;
  int m0 = tile * 32;

  floatx4 acc[2][8];
#pragma unroll
  for (int a = 0; a < 2; ++a)
#pragma unroll
    for (int b = 0; b < 8; ++b) acc[a][b] = floatx4{0.f, 0.f, 0.f, 0.f};

  int row[2];
#pragma unroll
  for (int mt = 0; mt < 2; ++mt) {
    int r = m0 + mt * 16 + col;
    row[mt] = r < M ? r : M - 1;
  }

  // stage W hi+lo: 2048 units per plane
#pragma unroll
  for (int i = 0; i < 4; ++i) {
    int u = i * 512 + t;
    int g = u >> 8, q = (u >> 4) & 15, c = u & 15;
    size_t off = (size_t)(g * 16 + c) * 128 + q * 8;
    char* dst = (char*)Wlds + (size_t)(i * 512 + w * 64) * 16;
    __builtin_amdgcn_global_load_lds(
        (const __attribute__((address_space(1))) void*)(Wh + off),
        (__attribute__((address_space(3))) void*)dst, 16, 0, 0);
    __builtin_amdgcn_global_load_lds(
        (const __attribute__((address_space(1))) void*)(Wl + off),
        (__attribute__((address_space(3))) void*)(dst + 32768), 16, 0, 0);
  }

  // prefetch ALL A fragments (4 chunks x 2 mt x 2 planes = 256 B/lane)
  short8 pah[4][2], pal[4][2];
#pragma unroll
  for (int ck = 0; ck < 4; ++ck)
#pragma unroll
    for (int mt = 0; mt < 2; ++mt) {
      size_t off = (size_t)row[mt] * 128 + ck * 32 + quad * 8;
      pah[ck][mt] = *(const short8*)(Ah + off);
      pal[ck][mt] = *(const short8*)(Al + off);
    }

  __syncthreads();                         // W valid

#pragma unroll
  for (int ck = 0; ck < 4; ++ck) {
#pragma unroll
    for (int nt = 0; nt < 8; ++nt) {
      int u = (nt * 16 + ck * 4 + quad) * 16 + col;
      short8 bh = Wlds[u];
      short8 bl = Wlds[2048 + u];
#pragma unroll
      for (int mt = 0; mt < 2; ++mt) {
        acc[mt][nt] = __builtin_amdgcn_mfma_f32_16x16x32_bf16(pah[ck][mt], bh, acc[mt][nt], 0, 0, 0);
        acc[mt][nt] = __builtin_amdgcn_mfma_f32_16x16x32_bf16(pal[ck][mt], bh, acc[mt][nt], 0, 0, 0);
        acc[mt][nt] = __builtin_amdgcn_mfma_f32_16x16x32_bf16(pah[ck][mt], bl, acc[mt][nt], 0, 0, 0);
      }
    }
  }

#pragma unroll
  for (int mt = 0; mt < 2; ++mt)
#pragma unroll
    for (int r = 0; r < 4; ++r) {
      int m = m0 + mt * 16 + quad * 4 + r;
      if (m < M) {
#pragma unroll
        for (int nt = 0; nt < 8; ++nt)
          C[(size_t)m * NFEAT + nt * 16 + col] = acc[mt][nt][r];
      }
    }
}

// ---------------- Aggregation ----------------
// m rows already carry dis[src]; out[i] = relu(dis[i]*(sum_{s->i} m[s] + m[i]) + b).
// Half-wave (32 lanes, float4) per node; 4-deep unroll -> 8 gathers in flight/wave.
// MODE 0: write next-layer input = dis[i]*out as bf16 hi/lo.  MODE 1: fp32 out.

template<int MODE>
__global__ __launch_bounds__(256)
void agg_kernel(const float* __restrict__ m, const int* __restrict__ row_ptr,
                const int* __restrict__ csr_src, const float* __restrict__ dis,
                const float* __restrict__ bias,
                unsigned int* __restrict__ out_h, unsigned int* __restrict__ out_l,
                float* __restrict__ out_f, int Nn) {
  int t = threadIdx.x;
  int w = t >> 6, lane = t & 63;
  int sub = lane >> 5, l = lane & 31;
  int i = blockIdx.x * 8 + w * 2 + sub;
  if (i >= Nn) return;
  const float4* m4 = (const float4*)m;
  float4 acc = m4[(size_t)i * 32 + l];             // self-loop term
  int e0 = row_ptr[i], e1 = row_ptr[i + 1];
  int e = e0;
  for (; e + 4 <= e1; e += 4) {
    int s0 = csr_src[e], s1 = csr_src[e + 1], s2 = csr_src[e + 2], s3 = csr_src[e + 3];
    float4 v0 = m4[(size_t)s0 * 32 + l];
    float4 v1 = m4[(size_t)s1 * 32 + l];
    float4 v2 = m4[(size_t)s2 * 32 + l];
    float4 v3 = m4[(size_t)s3 * 32 + l];
    acc.x += (v0.x + v1.x) + (v2.x + v3.x);
    acc.y += (v0.y + v1.y) + (v2.y + v3.y);
    acc.z += (v0.z + v1.z) + (v2.z + v3.z);
    acc.w += (v0.w + v1.w) + (v2.w + v3.w);
  }
  for (; e < e1; ++e) {
    int s = csr_src[e];
    float4 v = m4[(size_t)s * 32 + l];
    acc.x += v.x; acc.y += v.y; acc.z += v.z; acc.w += v.w;
  }
  float di = dis[i];
  float4 b = ((const float4*)bias)[l];
  float r0 = fmaxf(fmaf(di, acc.x, b.x), 0.f);
  float r1 = fmaxf(fmaf(di, acc.y, b.y), 0.f);
  float r2 = fmaxf(fmaf(di, acc.z, b.z), 0.f);
  float r3 = fmaxf(fmaf(di, acc.w, b.w), 0.f);
  if (MODE == 0) {
    unsigned short h0, l0, h1, l1, h2, l2, h3, l3;
    split1(di * r0, h0, l0);
    split1(di * r1, h1, l1);
    split1(di * r2, h2, l2);
    split1(di * r3, h3, l3);
    uint2 ph = make_uint2((unsigned int)h0 | ((unsigned int)h1 << 16),
                          (unsigned int)h2 | ((unsigned int)h3 << 16));
    uint2 pl = make_uint2((unsigned int)l0 | ((unsigned int)l1 << 16),
                          (unsigned int)l2 | ((unsigned int)l3 << 16));
    ((uint2*)out_h)[(size_t)i * 32 + l] = ph;
    ((uint2*)out_l)[(size_t)i * 32 + l] = pl;
  } else {
    ((float4*)out_f)[(size_t)i * 32 + l] = make_float4(r0, r1, r2, r3);
  }
}

// ---------------- Prototype head via MFMA ----------------

__global__ __launch_bounds__(256)
void proto_mfma(const float* __restrict__ emb,
                const unsigned short* __restrict__ Ph, const unsigned short* __restrict__ Pl,
                const float* __restrict__ pn, const float* __restrict__ lastw,
                float* __restrict__ out_logits, float* __restrict__ out_probs,
                float* __restrict__ out_dist, int Nn) {
  __shared__ float simS[64][65];
  int t = threadIdx.x;
  int w = t >> 6, lane = t & 63;
  int col = lane & 15, quad = lane >> 4;
  int m0 = blockIdx.x * 64 + w * 16;
  int row = m0 + col;
  int r0 = row < Nn ? row : Nn - 1;

  floatx4 acc[4];
#pragma unroll
  for (int nt = 0; nt < 4; ++nt) acc[nt] = floatx4{0.f, 0.f, 0.f, 0.f};

  float en = 0.f;
  const float* ap = emb + (size_t)r0 * 128 + quad * 8;
#pragma unroll
  for (int kc = 0; kc < 4; ++kc) {
    float4 va = *(const float4*)(ap + kc * 32);
    float4 vb = *(const float4*)(ap + kc * 32 + 4);
    float f[8] = {va.x, va.y, va.z, va.w, vb.x, vb.y, vb.z, vb.w};
    short8 ah, al;
#pragma unroll
    for (int j = 0; j < 8; ++j) {
      unsigned short h, l;
      split1(f[j], h, l);
      ah[j] = (short)h; al[j] = (short)l;
      en = fmaf(f[j], f[j], en);
    }
#pragma unroll
    for (int nt = 0; nt < 4; ++nt) {
      const unsigned short* bp = Ph + (size_t)(nt * 16 + col) * 128 + kc * 32 + quad * 8;
      const unsigned short* bq = Pl + (size_t)(nt * 16 + col) * 128 + kc * 32 + quad * 8;
      short8 bh = *(const short8*)bp;
      short8 bl = *(const short8*)bq;
      acc[nt] = __builtin_amdgcn_mfma_f32_16x16x32_bf16(ah, bh, acc[nt], 0, 0, 0);
      acc[nt] = __builtin_amdgcn_mfma_f32_16x16x32_bf16(al, bh, acc[nt], 0, 0, 0);
      acc[nt] = __builtin_amdgcn_mfma_f32_16x16x32_bf16(ah, bl, acc[nt], 0, 0, 0);
    }
  }
  en += __shfl_xor(en, 16);
  en += __shfl_xor(en, 32);

  float pnv[4];
#pragma unroll
  for (int nt = 0; nt < 4; ++nt) pnv[nt] = pn[nt * 16 + col];

#pragma unroll
  for (int r = 0; r < 4; ++r) {
    int node = m0 + quad * 4 + r;
    float enr = __shfl(en, quad * 4 + r);
    bool valid = node < Nn;
#pragma unroll
    for (int nt = 0; nt < 4; ++nt) {
      int p = nt * 16 + col;
      float d = enr - 2.f * acc[nt][r] + pnv[nt];
      float sim = (p < NPROTO) ? logf((d + 1.0f) / (d + 1e-4f)) : 0.f;
      simS[w * 16 + quad * 4 + r][p] = sim;
      if (valid && p < NPROTO) out_dist[(size_t)node * NPROTO + p] = d;
    }
  }
  __syncthreads();

  if (t < 64) {
    int node = blockIdx.x * 64 + t;
    if (node < Nn) {
      float sims[NPROTO];
#pragma unroll
      for (int p = 0; p < NPROTO; ++p) sims[p] = simS[t][p];
      float lg[NCLS];
      float mx = -1e30f;
#pragma unroll
      for (int c = 0; c < NCLS; ++c) {
        float s = 0.f;
#pragma unroll
        for (int p = 0; p < NPROTO; ++p) s = fmaf(sims[p], lastw[c * NPROTO + p], s);
        lg[c] = s;
        mx = fmaxf(mx, s);
      }
      float ss = 0.f;
#pragma unroll
      for (int c = 0; c < NCLS; ++c) ss += expf(lg[c] - mx);
      float inv = 1.f / ss;
#pragma unroll
      for (int c = 0; c < NCLS; ++c) {
        out_logits[(size_t)node * NCLS + c] = lg[c];
        out_probs[(size_t)node * NCLS + c] = expf(lg[c] - mx) * inv;
      }
    }
  }
}

// ---------------- launcher ----------------

extern "C" void kernel_launch(void* const* d_in, const int* in_sizes, int n_in,
                              void* d_out, int out_size, void* d_ws, size_t ws_size,
                              hipStream_t stream) {
  const float* x    = (const float*)d_in[0];
  const int*  eidx  = (const int*)d_in[1];
  const float* W1   = (const float*)d_in[2];
  const float* b1   = (const float*)d_in[3];
  const float* W2   = (const float*)d_in[4];
  const float* b2   = (const float*)d_in[5];
  const float* W3   = (const float*)d_in[6];
  const float* b3   = (const float*)d_in[7];
  const float* prot = (const float*)d_in[8];
  const float* lastw= (const float*)d_in[9];

  const int Nn = in_sizes[0] / 512;       // 50000
  const int E  = in_sizes[1] / 2;         // 640000
  const int* esrc = eidx;
  const int* edst = eidx + E;

  float* out        = (float*)d_out;
  float* out_logits = out;
  float* out_probs  = out + (size_t)Nn * NCLS;
  float* out_emb    = out + (size_t)Nn * 2 * NCLS;
  float* out_dist   = out_emb + (size_t)Nn * NFEAT;

  // workspace layout
  float* mbuf  = (float*)d_ws;                              // N*128 fp32
  unsigned int* hh = (unsigned int*)(mbuf + (size_t)Nn * NFEAT);
  unsigned int* hl = hh + (size_t)Nn * 64;
  unsigned short* W1h = (unsigned short*)(hl + (size_t)Nn * 64);   // 128*512
  unsigned short* W1l = W1h + 128 * 512;
  unsigned short* W2h = W1l + 128 * 512;                            // 128*128
  unsigned short* W2l = W2h + 128 * 128;
  unsigned short* W3h = W2l + 128 * 128;
  unsigned short* W3l = W3h + 128 * 128;
  unsigned short* Ph  = W3l + 128 * 128;                            // 64*128
  unsigned short* Pl  = Ph + 64 * 128;
  float* pn    = (float*)(Pl + 64 * 128);                   // 64
  int* cnt     = (int*)(pn + 64);                           // N
  float* dis   = (float*)(cnt + Nn);                        // N
  int* row_ptr = (int*)(dis + Nn);                          // N+1
  int* cursor  = row_ptr + Nn + 1;                          // N
  int* csr_src = cursor + Nn;                               // E

  hipMemsetAsync(cnt, 0, Nn * sizeof(int), stream);
  hipMemsetAsync(cursor, 0, Nn * sizeof(int), stream);
  count_kernel<<<(E + 255) / 256, 256, 0, stream>>>(edst, cnt, E);
  scan_kernel<<<1, 1024, 0, stream>>>(cnt, row_ptr, Nn);
  dis_kernel<<<(Nn + 255) / 256, 256, 0, stream>>>(cnt, dis, Nn);
  fill_kernel<<<(E + 255) / 256, 256, 0, stream>>>(esrc, edst, row_ptr, cursor, csr_src, E);

  wconv_kernel<<<(128 * 512 + 255) / 256, 256, 0, stream>>>(W1, W1h, W1l, 128 * 512);
  wconv_kernel<<<(128 * 128 + 255) / 256, 256, 0, stream>>>(W2, W2h, W2l, 128 * 128);
  wconv_kernel<<<(128 * 128 + 255) / 256, 256, 0, stream>>>(W3, W3h, W3l, 128 * 128);
  psplit_kernel<<<1, 128, 0, stream>>>(prot, Ph, Pl, pn);

  int ntiles = (Nn + 31) / 32;
  int gblocks = (ntiles + 7) / 8;          // 8 waves/block, 1 tile/wave
  int ablocks = (Nn + 7) / 8;
  // layer 1: m = (dis . x) @ W1^T  (persistent W1-hi, barrier-free K-loop)
  gemm_p1<<<gblocks, 512, 0, stream>>>(x, dis, W1h, mbuf, Nn);
  agg_kernel<0><<<ablocks, 256, 0, stream>>>(mbuf, row_ptr, csr_src, dis, b1, hh, hl, nullptr, Nn);
  // layer 2
  gemm_p2<<<gblocks, 512, 0, stream>>>((const unsigned short*)hh, (const unsigned short*)hl,
                                       W2h, W2l, mbuf, Nn);
  agg_kernel<0><<<ablocks, 256, 0, stream>>>(mbuf, row_ptr, csr_src, dis, b2, hh, hl, nullptr, Nn);
  // layer 3 -> emb fp32 into d_out
  gemm_p2<<<gblocks, 512, 0, stream>>>((const unsigned short*)hh, (const unsigned short*)hl,
                                       W3h, W3l, mbuf, Nn);
  agg_kernel<1><<<ablocks, 256, 0, stream>>>(mbuf, row_ptr, csr_src, dis, b3, nullptr, nullptr, out_emb, Nn);

  proto_mfma<<<(Nn + 63) / 64, 256, 0, stream>>>(out_emb, Ph, Pl, pn, lastw,
                                                 out_logits, out_probs, out_dist, Nn);
}

// Round 9
// 496.979 us; speedup vs baseline: 1.4057x; 1.1344x over previous
//
#include <hip/hip_runtime.h>
#include <cstdint>
#include <cstddef>

#define NFEAT 128
#define NPROTO 50
#define NCLS 10

typedef __attribute__((ext_vector_type(8))) short short8;    // 8 x bf16
typedef __attribute__((ext_vector_type(4))) float floatx4;

// ---------------- CSR build ----------------

__global__ __launch_bounds__(256) void count_kernel(const int* __restrict__ dst,
                                                    int* __restrict__ cnt, int E) {
  int e = blockIdx.x * 256 + threadIdx.x;
  if (e < E) atomicAdd(&cnt[dst[e]], 1);
}

// 3-stage parallel exclusive scan of cnt -> row_ptr (+ fused dis in stage 3)

__global__ __launch_bounds__(256)
void scan1_kernel(const int* __restrict__ cnt, int* __restrict__ row_ptr,
                  int* __restrict__ btot, int Nn) {
  __shared__ int s[256];
  int t = threadIdx.x;
  int i = blockIdx.x * 256 + t;
  int v = (i < Nn) ? cnt[i] : 0;
  s[t] = v;
  __syncthreads();
#pragma unroll
  for (int off = 1; off < 256; off <<= 1) {
    int add = (t >= off) ? s[t - off] : 0;
    __syncthreads();
    s[t] += add;
    __syncthreads();
  }
  if (i < Nn) row_ptr[i] = s[t] - v;       // exclusive, block-local
  if (t == 255) btot[blockIdx.x] = s[255];
}

__global__ __launch_bounds__(256)
void scan2_kernel(const int* __restrict__ btot, int* __restrict__ boff,
                  int* __restrict__ row_ptr, int nb, int Nn) {
  __shared__ int s[256];
  int t = threadIdx.x;
  int v = (t < nb) ? btot[t] : 0;
  s[t] = v;
  __syncthreads();
#pragma unroll
  for (int off = 1; off < 256; off <<= 1) {
    int add = (t >= off) ? s[t - off] : 0;
    __syncthreads();
    s[t] += add;
    __syncthreads();
  }
  if (t < nb) boff[t] = s[t] - v;          // exclusive block offsets
  if (t == 255) row_ptr[Nn] = s[255];      // total edge count
}

__global__ __launch_bounds__(256)
void scan3_kernel(int* __restrict__ row_ptr, const int* __restrict__ boff,
                  const int* __restrict__ cnt, float* __restrict__ dis, int Nn) {
  int i = blockIdx.x * 256 + threadIdx.x;
  if (i < Nn) {
    row_ptr[i] += boff[blockIdx.x];
    dis[i] = 1.0f / sqrtf((float)(cnt[i] + 1));   // +1: self-loop
  }
}

__global__ __launch_bounds__(256) void fill_kernel(const int* __restrict__ src,
                                                   const int* __restrict__ dst,
                                                   const int* __restrict__ row_ptr,
                                                   int* __restrict__ cursor,
                                                   int* __restrict__ csr_src, int E) {
  int e = blockIdx.x * 256 + threadIdx.x;
  if (e < E) {
    int d = dst[e];
    int pos = atomicAdd(&cursor[d], 1);
    csr_src[row_ptr[d] + pos] = src[e];
  }
}

// ---------------- fp32 -> bf16 hi/lo split ----------------

__device__ __forceinline__ void split1(float v, unsigned short& h, unsigned short& l) {
  unsigned int b = __float_as_uint(v);
  h = (unsigned short)(b >> 16);
  float r = v - __uint_as_float(b & 0xFFFF0000u);
  l = (unsigned short)(__float_as_uint(r) >> 16);
}

__global__ __launch_bounds__(256) void wconv_kernel(const float* __restrict__ W,
                                                    unsigned short* __restrict__ Wh,
                                                    unsigned short* __restrict__ Wl, int n) {
  int i = blockIdx.x * 256 + threadIdx.x;
  if (i < n) {
    unsigned short h, l;
    split1(W[i], h, l);
    Wh[i] = h; Wl[i] = l;
  }
}

// protos: split to bf16 hi/lo padded to 64 rows, plus squared norms
__global__ __launch_bounds__(128)
void psplit_kernel(const float* __restrict__ proto, unsigned short* __restrict__ Ph,
                   unsigned short* __restrict__ Pl, float* __restrict__ pn) {
  int t = threadIdx.x;
  for (int idx = t; idx < 64 * 128; idx += 128) {
    int p = idx >> 7;
    float v = (p < NPROTO) ? proto[p * 128 + (idx & 127)] : 0.f;
    unsigned short h, l;
    split1(v, h, l);
    Ph[idx] = h; Pl[idx] = l;
  }
  if (t < 64) {
    float s = 0.f;
    if (t < NPROTO)
      for (int f = 0; f < 128; ++f) { float v = proto[t * 128 + f]; s += v * v; }
    pn[t] = s;
  }
}

// ---------------- persistent-W streaming GEMM, layer 1 ----------------
// C[M,128] = (dis.*A[M,512]) @ W1[128,512]^T, W1 as bf16-hi only (2-product
// split on A keeps A at fp32 precision; W rounding ~2^-9 rel).
// Block = 512 thr = 8 waves; wave = one 32-row tile x 128 cols, fully
// independent K-loop: NO barriers inside (only 2, around the W-phase loads).
// W phase (256 k) lives in LDS fragment-linear (conflict-free b128 reads).
// A streams through a depth-4 rolling register prefetch (16 loads in flight).

__global__ __launch_bounds__(512, 2)
void gemm_p1(const float* __restrict__ A, const float* __restrict__ dis,
             const unsigned short* __restrict__ Wh,
             float* __restrict__ C, int M) {
  __shared__ short8 Wlds[4096];            // 64 KB: one 128x256 bf16 W phase
  int t = threadIdx.x;
  int w = t >> 6, lane = t & 63;
  int col = lane & 15, quad = lane >> 4;
  int ntiles = (M + 31) >> 5;
  int tile = blockIdx.x * 8 + w;
  if (tile >= ntiles) tile = ntiles - 1;   // dup of last tile: benign same-value stores
  int m0 = tile * 32;

  floatx4 acc[2][8];
#pragma unroll
  for (int a = 0; a < 2; ++a)
#pragma unroll
    for (int b = 0; b < 8; ++b) acc[a][b] = floatx4{0.f, 0.f, 0.f, 0.f};

  int row[2]; float dsc[2];
#pragma unroll
  for (int mt = 0; mt < 2; ++mt) {
    int r = m0 + mt * 16 + col;
    row[mt] = r < M ? r : M - 1;
    dsc[mt] = dis[row[mt]];
  }

  for (int p = 0; p < 2; ++p) {
    const int kb = p * 256;
    // ---- stage W phase: 4096 units, fragment-linear (g,q,c) ----
    __syncthreads();                       // phase p-1 consumers done
#pragma unroll
    for (int i = 0; i < 8; ++i) {
      int u = i * 512 + t;
      int g = u >> 9, q = (u >> 4) & 31, c = u & 15;
      const unsigned short* src = Wh + (size_t)(g * 16 + c) * 512 + kb + q * 8;
      __builtin_amdgcn_global_load_lds(
          (const __attribute__((address_space(1))) void*)src,
          (__attribute__((address_space(3))) void*)((char*)Wlds + (size_t)(i * 512 + w * 64) * 16),
          16, 0, 0);
    }
    __syncthreads();                       // W phase valid

    // ---- stream 8 chunks of 32 k, depth-4 rolling prefetch ----
    float4 pf[4][2][2];                    // [slot][mt][half]
#pragma unroll
    for (int c0 = 0; c0 < 4; ++c0)
#pragma unroll
      for (int mt = 0; mt < 2; ++mt) {
        const float* pp = A + (size_t)row[mt] * 512 + kb + c0 * 32 + quad * 8;
        pf[c0][mt][0] = *(const float4*)pp;
        pf[c0][mt][1] = *(const float4*)(pp + 4);
      }
#pragma unroll
    for (int ck = 0; ck < 8; ++ck) {
      short8 ah[2], al[2];
#pragma unroll
      for (int mt = 0; mt < 2; ++mt) {
        float4 va = pf[ck & 3][mt][0];
        float4 vb = pf[ck & 3][mt][1];
        float f[8] = {va.x, va.y, va.z, va.w, vb.x, vb.y, vb.z, vb.w};
#pragma unroll
        for (int j = 0; j < 8; ++j) {
          unsigned short h, l;
          split1(f[j] * dsc[mt], h, l);
          ah[mt][j] = (short)h; al[mt][j] = (short)l;
        }
      }
      if (ck + 4 < 8) {
#pragma unroll
        for (int mt = 0; mt < 2; ++mt) {
          const float* pp = A + (size_t)row[mt] * 512 + kb + (ck + 4) * 32 + quad * 8;
          pf[ck & 3][mt][0] = *(const float4*)pp;
          pf[ck & 3][mt][1] = *(const float4*)(pp + 4);
        }
      }
#pragma unroll
      for (int nt = 0; nt < 8; ++nt) {
        int u = (nt * 32 + ck * 4 + quad) * 16 + col;
        short8 bh = Wlds[u];
#pragma unroll
        for (int mt = 0; mt < 2; ++mt) {
          acc[mt][nt] = __builtin_amdgcn_mfma_f32_16x16x32_bf16(ah[mt], bh, acc[mt][nt], 0, 0, 0);
          acc[mt][nt] = __builtin_amdgcn_mfma_f32_16x16x32_bf16(al[mt], bh, acc[mt][nt], 0, 0, 0);
        }
      }
    }
  }

#pragma unroll
  for (int mt = 0; mt < 2; ++mt)
#pragma unroll
    for (int r = 0; r < 4; ++r) {
      int m = m0 + mt * 16 + quad * 4 + r;
      if (m < M) {
#pragma unroll
        for (int nt = 0; nt < 8; ++nt)
          C[(size_t)m * NFEAT + nt * 16 + col] = acc[mt][nt][r];
      }
    }
}

// ---------------- persistent-W streaming GEMM, layers 2/3 ----------------
// C[M,128] = A@W^T, A pre-split bf16 hi/lo (pre-scaled), W hi+lo in LDS
// (64 KB, single load), 3-product split. One barrier pair total.

__global__ __launch_bounds__(512, 2)
void gemm_p2(const unsigned short* __restrict__ Ah, const unsigned short* __restrict__ Al,
             const unsigned short* __restrict__ Wh, const unsigned short* __restrict__ Wl,
             float* __restrict__ C, int M) {
  __shared__ short8 Wlds[4096];            // [plane 2][g 8][q 16][c 16]
  int t = threadIdx.x;
  int w = t >> 6, lane = t & 63;
  int col = lane & 15, quad = lane >> 4;
  int ntiles = (M + 31) >> 5;
  int tile = blockIdx.x * 8 + w;
  if (tile >= ntiles) tile = ntiles - 1;
  int m0 = tile * 32;

  floatx4 acc[2][8];
#pragma unroll
  for (int a = 0; a < 2; ++a)
#pragma unroll
    for (int b = 0; b < 8; ++b) acc[a][b] = floatx4{0.f, 0.f, 0.f, 0.f};

  int row[2];
#pragma unroll
  for (int mt = 0; mt < 2; ++mt) {
    int r = m0 + mt * 16 + col;
    row[mt] = r < M ? r : M - 1;
  }

  // stage W hi+lo: 2048 units per plane
#pragma unroll
  for (int i = 0; i < 4; ++i) {
    int u = i * 512 + t;
    int g = u >> 8, q = (u >> 4) & 15, c = u & 15;
    size_t off = (size_t)(g * 16 + c) * 128 + q * 8;
    char* dst = (char*)Wlds + (size_t)(i * 512 + w * 64) * 16;
    __builtin_amdgcn_global_load_lds(
        (const __attribute__((address_space(1))) void*)(Wh + off),
        (__attribute__((address_space(3))) void*)dst, 16, 0, 0);
    __builtin_amdgcn_global_load_lds(
        (const __attribute__((address_space(1))) void*)(Wl + off),
        (__attribute__((address_space(3))) void*)(dst + 32768), 16, 0, 0);
  }

  // prefetch ALL A fragments (4 chunks x 2 mt x 2 planes = 256 B/lane)
  short8 pah[4][2], pal[4][2];
#pragma unroll
  for (int ck = 0; ck < 4; ++ck)
#pragma unroll
    for (int mt = 0; mt < 2; ++mt) {
      size_t off = (size_t)row[mt] * 128 + ck * 32 + quad * 8;
      pah[ck][mt] = *(const short8*)(Ah + off);
      pal[ck][mt] = *(const short8*)(Al + off);
    }

  __syncthreads();                         // W valid

#pragma unroll
  for (int ck = 0; ck < 4; ++ck) {
#pragma unroll
    for (int nt = 0; nt < 8; ++nt) {
      int u = (nt * 16 + ck * 4 + quad) * 16 + col;
      short8 bh = Wlds[u];
      short8 bl = Wlds[2048 + u];
#pragma unroll
      for (int mt = 0; mt < 2; ++mt) {
        acc[mt][nt] = __builtin_amdgcn_mfma_f32_16x16x32_bf16(pah[ck][mt], bh, acc[mt][nt], 0, 0, 0);
        acc[mt][nt] = __builtin_amdgcn_mfma_f32_16x16x32_bf16(pal[ck][mt], bh, acc[mt][nt], 0, 0, 0);
        acc[mt][nt] = __builtin_amdgcn_mfma_f32_16x16x32_bf16(pah[ck][mt], bl, acc[mt][nt], 0, 0, 0);
      }
    }
  }

#pragma unroll
  for (int mt = 0; mt < 2; ++mt)
#pragma unroll
    for (int r = 0; r < 4; ++r) {
      int m = m0 + mt * 16 + quad * 4 + r;
      if (m < M) {
#pragma unroll
        for (int nt = 0; nt < 8; ++nt)
          C[(size_t)m * NFEAT + nt * 16 + col] = acc[mt][nt][r];
      }
    }
}

// ---------------- Aggregation ----------------
// m rows already carry dis[src]; out[i] = relu(dis[i]*(sum_{s->i} m[s] + m[i]) + b).
// Half-wave (32 lanes, float4) per node; 4-deep unroll -> 8 gathers in flight/wave.
// MODE 0: write next-layer input = dis[i]*out as bf16 hi/lo.  MODE 1: fp32 out.

template<int MODE>
__global__ __launch_bounds__(256)
void agg_kernel(const float* __restrict__ m, const int* __restrict__ row_ptr,
                const int* __restrict__ csr_src, const float* __restrict__ dis,
                const float* __restrict__ bias,
                unsigned int* __restrict__ out_h, unsigned int* __restrict__ out_l,
                float* __restrict__ out_f, int Nn) {
  int t = threadIdx.x;
  int w = t >> 6, lane = t & 63;
  int sub = lane >> 5, l = lane & 31;
  int i = blockIdx.x * 8 + w * 2 + sub;
  if (i >= Nn) return;
  const float4* m4 = (const float4*)m;
  float4 acc = m4[(size_t)i * 32 + l];             // self-loop term
  int e0 = row_ptr[i], e1 = row_ptr[i + 1];
  int e = e0;
  for (; e + 4 <= e1; e += 4) {
    int s0 = csr_src[e], s1 = csr_src[e + 1], s2 = csr_src[e + 2], s3 = csr_src[e + 3];
    float4 v0 = m4[(size_t)s0 * 32 + l];
    float4 v1 = m4[(size_t)s1 * 32 + l];
    float4 v2 = m4[(size_t)s2 * 32 + l];
    float4 v3 = m4[(size_t)s3 * 32 + l];
    acc.x += (v0.x + v1.x) + (v2.x + v3.x);
    acc.y += (v0.y + v1.y) + (v2.y + v3.y);
    acc.z += (v0.z + v1.z) + (v2.z + v3.z);
    acc.w += (v0.w + v1.w) + (v2.w + v3.w);
  }
  for (; e < e1; ++e) {
    int s = csr_src[e];
    float4 v = m4[(size_t)s * 32 + l];
    acc.x += v.x; acc.y += v.y; acc.z += v.z; acc.w += v.w;
  }
  float di = dis[i];
  float4 b = ((const float4*)bias)[l];
  float r0 = fmaxf(fmaf(di, acc.x, b.x), 0.f);
  float r1 = fmaxf(fmaf(di, acc.y, b.y), 0.f);
  float r2 = fmaxf(fmaf(di, acc.z, b.z), 0.f);
  float r3 = fmaxf(fmaf(di, acc.w, b.w), 0.f);
  if (MODE == 0) {
    unsigned short h0, l0, h1, l1, h2, l2, h3, l3;
    split1(di * r0, h0, l0);
    split1(di * r1, h1, l1);
    split1(di * r2, h2, l2);
    split1(di * r3, h3, l3);
    uint2 ph = make_uint2((unsigned int)h0 | ((unsigned int)h1 << 16),
                          (unsigned int)h2 | ((unsigned int)h3 << 16));
    uint2 pl = make_uint2((unsigned int)l0 | ((unsigned int)l1 << 16),
                          (unsigned int)l2 | ((unsigned int)l3 << 16));
    ((uint2*)out_h)[(size_t)i * 32 + l] = ph;
    ((uint2*)out_l)[(size_t)i * 32 + l] = pl;
  } else {
    ((float4*)out_f)[(size_t)i * 32 + l] = make_float4(r0, r1, r2, r3);
  }
}

// ---------------- Prototype head via MFMA ----------------

__global__ __launch_bounds__(256)
void proto_mfma(const float* __restrict__ emb,
                const unsigned short* __restrict__ Ph, const unsigned short* __restrict__ Pl,
                const float* __restrict__ pn, const float* __restrict__ lastw,
                float* __restrict__ out_logits, float* __restrict__ out_probs,
                float* __restrict__ out_dist, int Nn) {
  __shared__ float simS[64][65];
  int t = threadIdx.x;
  int w = t >> 6, lane = t & 63;
  int col = lane & 15, quad = lane >> 4;
  int m0 = blockIdx.x * 64 + w * 16;
  int row = m0 + col;
  int r0 = row < Nn ? row : Nn - 1;

  floatx4 acc[4];
#pragma unroll
  for (int nt = 0; nt < 4; ++nt) acc[nt] = floatx4{0.f, 0.f, 0.f, 0.f};

  float en = 0.f;
  const float* ap = emb + (size_t)r0 * 128 + quad * 8;
#pragma unroll
  for (int kc = 0; kc < 4; ++kc) {
    float4 va = *(const float4*)(ap + kc * 32);
    float4 vb = *(const float4*)(ap + kc * 32 + 4);
    float f[8] = {va.x, va.y, va.z, va.w, vb.x, vb.y, vb.z, vb.w};
    short8 ah, al;
#pragma unroll
    for (int j = 0; j < 8; ++j) {
      unsigned short h, l;
      split1(f[j], h, l);
      ah[j] = (short)h; al[j] = (short)l;
      en = fmaf(f[j], f[j], en);
    }
#pragma unroll
    for (int nt = 0; nt < 4; ++nt) {
      const unsigned short* bp = Ph + (size_t)(nt * 16 + col) * 128 + kc * 32 + quad * 8;
      const unsigned short* bq = Pl + (size_t)(nt * 16 + col) * 128 + kc * 32 + quad * 8;
      short8 bh = *(const short8*)bp;
      short8 bl = *(const short8*)bq;
      acc[nt] = __builtin_amdgcn_mfma_f32_16x16x32_bf16(ah, bh, acc[nt], 0, 0, 0);
      acc[nt] = __builtin_amdgcn_mfma_f32_16x16x32_bf16(al, bh, acc[nt], 0, 0, 0);
      acc[nt] = __builtin_amdgcn_mfma_f32_16x16x32_bf16(ah, bl, acc[nt], 0, 0, 0);
    }
  }
  en += __shfl_xor(en, 16);
  en += __shfl_xor(en, 32);

  float pnv[4];
#pragma unroll
  for (int nt = 0; nt < 4; ++nt) pnv[nt] = pn[nt * 16 + col];

#pragma unroll
  for (int r = 0; r < 4; ++r) {
    int node = m0 + quad * 4 + r;
    float enr = __shfl(en, quad * 4 + r);
    bool valid = node < Nn;
#pragma unroll
    for (int nt = 0; nt < 4; ++nt) {
      int p = nt * 16 + col;
      float d = enr - 2.f * acc[nt][r] + pnv[nt];
      float sim = (p < NPROTO) ? logf((d + 1.0f) / (d + 1e-4f)) : 0.f;
      simS[w * 16 + quad * 4 + r][p] = sim;
      if (valid && p < NPROTO) out_dist[(size_t)node * NPROTO + p] = d;
    }
  }
  __syncthreads();

  if (t < 64) {
    int node = blockIdx.x * 64 + t;
    if (node < Nn) {
      float sims[NPROTO];
#pragma unroll
      for (int p = 0; p < NPROTO; ++p) sims[p] = simS[t][p];
      float lg[NCLS];
      float mx = -1e30f;
#pragma unroll
      for (int c = 0; c < NCLS; ++c) {
        float s = 0.f;
#pragma unroll
        for (int p = 0; p < NPROTO; ++p) s = fmaf(sims[p], lastw[c * NPROTO + p], s);
        lg[c] = s;
        mx = fmaxf(mx, s);
      }
      float ss = 0.f;
#pragma unroll
      for (int c = 0; c < NCLS; ++c) ss += expf(lg[c] - mx);
      float inv = 1.f / ss;
#pragma unroll
      for (int c = 0; c < NCLS; ++c) {
        out_logits[(size_t)node * NCLS + c] = lg[c];
        out_probs[(size_t)node * NCLS + c] = expf(lg[c] - mx) * inv;
      }
    }
  }
}

// ---------------- launcher ----------------

extern "C" void kernel_launch(void* const* d_in, const int* in_sizes, int n_in,
                              void* d_out, int out_size, void* d_ws, size_t ws_size,
                              hipStream_t stream) {
  const float* x    = (const float*)d_in[0];
  const int*  eidx  = (const int*)d_in[1];
  const float* W1   = (const float*)d_in[2];
  const float* b1   = (const float*)d_in[3];
  const float* W2   = (const float*)d_in[4];
  const float* b2   = (const float*)d_in[5];
  const float* W3   = (const float*)d_in[6];
  const float* b3   = (const float*)d_in[7];
  const float* prot = (const float*)d_in[8];
  const float* lastw= (const float*)d_in[9];

  const int Nn = in_sizes[0] / 512;       // 50000
  const int E  = in_sizes[1] / 2;         // 640000
  const int* esrc = eidx;
  const int* edst = eidx + E;

  float* out        = (float*)d_out;
  float* out_logits = out;
  float* out_probs  = out + (size_t)Nn * NCLS;
  float* out_emb    = out + (size_t)Nn * 2 * NCLS;
  float* out_dist   = out_emb + (size_t)Nn * NFEAT;

  // workspace layout
  float* mbuf  = (float*)d_ws;                              // N*128 fp32
  unsigned int* hh = (unsigned int*)(mbuf + (size_t)Nn * NFEAT);
  unsigned int* hl = hh + (size_t)Nn * 64;
  unsigned short* W1h = (unsigned short*)(hl + (size_t)Nn * 64);   // 128*512
  unsigned short* W1l = W1h + 128 * 512;
  unsigned short* W2h = W1l + 128 * 512;                            // 128*128
  unsigned short* W2l = W2h + 128 * 128;
  unsigned short* W3h = W2l + 128 * 128;
  unsigned short* W3l = W3h + 128 * 128;
  unsigned short* Ph  = W3l + 128 * 128;                            // 64*128
  unsigned short* Pl  = Ph + 64 * 128;
  float* pn    = (float*)(Pl + 64 * 128);                   // 64
  int* cnt     = (int*)(pn + 64);                           // N
  float* dis   = (float*)(cnt + Nn);                        // N
  int* row_ptr = (int*)(dis + Nn);                          // N+1
  int* cursor  = row_ptr + Nn + 1;                          // N
  int* btot    = cursor + Nn;                               // ~256
  int* boff    = btot + 256;                                // ~256
  int* csr_src = boff + 256;                                // E

  const int nb = (Nn + 255) / 256;        // scan tiles (<= 256)

  hipMemsetAsync(cnt, 0, Nn * sizeof(int), stream);
  hipMemsetAsync(cursor, 0, Nn * sizeof(int), stream);
  count_kernel<<<(E + 255) / 256, 256, 0, stream>>>(edst, cnt, E);
  scan1_kernel<<<nb, 256, 0, stream>>>(cnt, row_ptr, btot, Nn);
  scan2_kernel<<<1, 256, 0, stream>>>(btot, boff, row_ptr, nb, Nn);
  scan3_kernel<<<nb, 256, 0, stream>>>(row_ptr, boff, cnt, dis, Nn);
  fill_kernel<<<(E + 255) / 256, 256, 0, stream>>>(esrc, edst, row_ptr, cursor, csr_src, E);

  wconv_kernel<<<(128 * 512 + 255) / 256, 256, 0, stream>>>(W1, W1h, W1l, 128 * 512);
  wconv_kernel<<<(128 * 128 + 255) / 256, 256, 0, stream>>>(W2, W2h, W2l, 128 * 128);
  wconv_kernel<<<(128 * 128 + 255) / 256, 256, 0, stream>>>(W3, W3h, W3l, 128 * 128);
  psplit_kernel<<<1, 128, 0, stream>>>(prot, Ph, Pl, pn);

  int ntiles = (Nn + 31) / 32;
  int gblocks = (ntiles + 7) / 8;          // 8 waves/block, 1 tile/wave
  int ablocks = (Nn + 7) / 8;
  // layer 1: m = (dis . x) @ W1^T  (persistent W1-hi, barrier-free K-loop)
  gemm_p1<<<gblocks, 512, 0, stream>>>(x, dis, W1h, mbuf, Nn);
  agg_kernel<0><<<ablocks, 256, 0, stream>>>(mbuf, row_ptr, csr_src, dis, b1, hh, hl, nullptr, Nn);
  // layer 2
  gemm_p2<<<gblocks, 512, 0, stream>>>((const unsigned short*)hh, (const unsigned short*)hl,
                                       W2h, W2l, mbuf, Nn);
  agg_kernel<0><<<ablocks, 256, 0, stream>>>(mbuf, row_ptr, csr_src, dis, b2, hh, hl, nullptr, Nn);
  // layer 3 -> emb fp32 into d_out
  gemm_p2<<<gblocks, 512, 0, stream>>>((const unsigned short*)hh, (const unsigned short*)hl,
                                       W3h, W3l, mbuf, Nn);
  agg_kernel<1><<<ablocks, 256, 0, stream>>>(mbuf, row_ptr, csr_src, dis, b3, nullptr, nullptr, out_emb, Nn);

  proto_mfma<<<(Nn + 63) / 64, 256, 0, stream>>>(out_emb, Ph, Pl, pn, lastw,
                                                 out_logits, out_probs, out_dist, Nn);
}